// Round 9
// baseline (388.033 us; speedup 1.0000x reference)
//
#include <hip/hip_runtime.h>
#include <hip/hip_cooperative_groups.h>

namespace cg = cooperative_groups;

#define Bn 4
#define Nn 4096000
#define Kn 409664
#define R1c 3686400u
#define NSEL 409600u

// ---- ws offsets (u32 units) ----
#define H1_OFF 0          // B*2048
#define H2_OFF 8192       // B*2048
#define H3_OFF 16384      // B*1024
#define ZERO_WORDS 20480
#define ST_OFF 20480      // B*8: 0=P,1=rem,2=mid,3=rem2,4=k_hi,5=SELKEY
#define BC_OFF 20512      // B*1000 (above counts -> scanned bc)
#define GE_OFF 24512      // B*1000
#define GT_OFF 28512      // B*1000
#define GC_OFF 32512      // B*1000 (candidate count per block)
#define CNT_OFF 36512     // B

// ---- deterministic candidate slots inside `out` (u32 units) ----
#define CAPW 1024u

#define SCAP 768          // max buffered rows per scatter block

#define OUT_SP  ((size_t)Bn * Kn * 5)
#define OUT_VAL ((size_t)Bn * Kn * 9)

__device__ __forceinline__ unsigned fkey(float x) {
    unsigned u = __float_as_uint(x);
    return u ^ ((unsigned)((int)u >> 31) | 0x80000000u);
}
__device__ __forceinline__ float keyf(unsigned k) {
    unsigned u = (k & 0x80000000u) ? (k & 0x7FFFFFFFu) : ~k;
    return __uint_as_float(u);
}

// ---------------- histogram pass 1: top 11 bits ----------------
__device__ __forceinline__ void h1add(unsigned* h, unsigned cp, float v) {
    unsigned bin = fkey(v) >> 21;
    atomicAdd(&h[(cp << 11) + ((bin + (cp << 3)) & 2047u)], 1u);
}

__global__ void hist1_k(const float* __restrict__ cube, unsigned* __restrict__ ws) {
    __shared__ unsigned h[4 * 2048];
    int tid = threadIdx.x, blk = blockIdx.x;
    int b = blk / 250, c = blk % 250;
    unsigned cp = (unsigned)(tid & 3);
    for (int j = tid; j < 8192; j += 256) h[j] = 0;
    __syncthreads();
    const float4* p = (const float4*)(cube + (size_t)b * Nn + (size_t)c * 16384);
    for (int it = 0; it < 16; it += 4) {
        float4 v0 = p[(it + 0) * 256 + tid];
        float4 v1 = p[(it + 1) * 256 + tid];
        float4 v2 = p[(it + 2) * 256 + tid];
        float4 v3 = p[(it + 3) * 256 + tid];
        h1add(h, cp, v0.x); h1add(h, cp, v0.y); h1add(h, cp, v0.z); h1add(h, cp, v0.w);
        h1add(h, cp, v1.x); h1add(h, cp, v1.y); h1add(h, cp, v1.z); h1add(h, cp, v1.w);
        h1add(h, cp, v2.x); h1add(h, cp, v2.y); h1add(h, cp, v2.z); h1add(h, cp, v2.w);
        h1add(h, cp, v3.x); h1add(h, cp, v3.y); h1add(h, cp, v3.z); h1add(h, cp, v3.w);
    }
    __syncthreads();
    unsigned* g = ws + H1_OFF + b * 2048;
    for (int j = tid; j < 2048; j += 256) {
        unsigned s = 0;
#pragma unroll
        for (int k = 0; k < 4; ++k) s += h[(k << 11) + (((unsigned)j + (k << 3)) & 2047u)];
        if (s) atomicAdd(&g[j], s);
    }
}

// ---------------- pick bucket containing rank R1c ----------------
__global__ void pick1_k(unsigned* __restrict__ ws) {
    __shared__ unsigned sh[256];
    int tid = threadIdx.x, b = blockIdx.x;
    const unsigned* hist = ws + H1_OFF + b * 2048;
    unsigned loc[8], lsum = 0;
    for (int j = 0; j < 8; ++j) { loc[j] = hist[tid * 8 + j]; lsum += loc[j]; }
    sh[tid] = lsum; __syncthreads();
    for (int off = 1; off < 256; off <<= 1) {
        unsigned v = (tid >= off) ? sh[tid - off] : 0u; __syncthreads();
        sh[tid] += v; __syncthreads();
    }
    unsigned base = tid ? sh[tid - 1] : 0u;
    if (R1c >= base && R1c < base + lsum) {
        unsigned cacc = base;
        for (int j = 0; j < 8; ++j) {
            if (R1c < cacc + loc[j]) {
                ws[ST_OFF + b * 8 + 0] = (unsigned)(tid * 8 + j);
                ws[ST_OFF + b * 8 + 1] = R1c - cacc;
                break;
            }
            cacc += loc[j];
        }
    }
}

// ---------------- collect: deterministic slots, zero global atomics ----------------
__global__ void collect_k(const float* __restrict__ cube, unsigned* __restrict__ ou,
                          unsigned* __restrict__ ws) {
    __shared__ unsigned sha[4], shc[4];
    int tid = threadIdx.x, blk = blockIdx.x;
    int b = blk / 1000, c = blk % 1000;
    int lane = tid & 63, wid = tid >> 6;
    unsigned P = ws[ST_OFF + b * 8 + 0];
    const float4* pc = (const float4*)(cube + (size_t)b * Nn + (size_t)c * 4096 + (size_t)wid * 1024);
    unsigned kk[16];
#pragma unroll
    for (int t = 0; t < 4; ++t) {
        float4 v = pc[t * 64 + lane];
        kk[4 * t + 0] = fkey(v.x); kk[4 * t + 1] = fkey(v.y);
        kk[4 * t + 2] = fkey(v.z); kk[4 * t + 3] = fkey(v.w);
    }
    unsigned long long bc[16];
    unsigned wab = 0, wcn = 0;
#pragma unroll
    for (int j = 0; j < 16; ++j) {
        unsigned top = kk[j] >> 21;
        wab += (unsigned)__popcll(__ballot(top > P));
        bc[j] = __ballot(top == P);
        wcn += (unsigned)__popcll(bc[j]);
    }
    if (lane == 0) { sha[wid] = wab; shc[wid] = wcn; }
    __syncthreads();
    if (tid == 0) {
        ws[BC_OFF + b * 1000 + c] = sha[0] + sha[1] + sha[2] + sha[3];
        ws[GC_OFF + b * 1000 + c] = shc[0] + shc[1] + shc[2] + shc[3];
    }
    unsigned run = 0;
    for (int w = 0; w < wid; ++w) run += shc[w];
    unsigned long long lt = (1ull << lane) - 1ull;
    unsigned* dst = ou + (size_t)b * 1024000 + (size_t)c * 1024;
#pragma unroll
    for (int j = 0; j < 16; ++j) {
        bool m = (kk[j] >> 21) == P;
        unsigned r = run + (unsigned)__popcll(bc[j] & lt);
        if (m && r < CAPW) dst[r] = kk[j];
        run += (unsigned)__popcll(bc[j]);
    }
}

// ================= fused refine (cooperative) =================
// P1 hist(mid) -> P2 pick(mid) -> P3 hist(low) -> P4 pick(low,k_hi)
// -> P5 per-slot ge/gt -> P6 scan + SELKEY + CNT
__global__ void refine_k(const unsigned* __restrict__ ou, unsigned* __restrict__ ws) {
    __shared__ unsigned shm[2048];
    cg::grid_group grid = cg::this_grid();
    int tid = threadIdx.x, blk = blockIdx.x;
    int b = blk >> 6, g = blk & 63;
    int lane = tid & 63, wid = tid >> 6;

    // ---- P1: mid-bit histogram over candidate slots
    for (int j = tid; j < 2048; j += 256) shm[j] = 0;
    __syncthreads();
    for (int c = g; c < 1000; c += 64) {
        unsigned n = min(ws[GC_OFF + b * 1000 + c], CAPW);
        const unsigned* src = ou + (size_t)b * 1024000 + (size_t)c * 1024;
        for (unsigned i = tid; i < n; i += 256)
            atomicAdd(&shm[(src[i] >> 10) & 0x7FFu], 1u);
    }
    __syncthreads();
    {
        unsigned* gd = ws + H2_OFF + b * 2048;
        for (int j = tid; j < 2048; j += 256) if (shm[j]) atomicAdd(&gd[j], shm[j]);
    }
    grid.sync();

    // ---- P2: pick mid
    if (g == 0) {
        const unsigned* hist = ws + H2_OFF + b * 2048;
        unsigned r = ws[ST_OFF + b * 8 + 1];
        unsigned loc[8], lsum = 0;
        for (int j = 0; j < 8; ++j) { loc[j] = hist[tid * 8 + j]; lsum += loc[j]; }
        shm[tid] = lsum; __syncthreads();
        for (int off = 1; off < 256; off <<= 1) {
            unsigned v = (tid >= off) ? shm[tid - off] : 0u; __syncthreads();
            shm[tid] += v; __syncthreads();
        }
        unsigned base = tid ? shm[tid - 1] : 0u;
        if (r >= base && r < base + lsum) {
            unsigned cacc = base;
            for (int j = 0; j < 8; ++j) {
                if (r < cacc + loc[j]) {
                    ws[ST_OFF + b * 8 + 2] = (unsigned)(tid * 8 + j);
                    ws[ST_OFF + b * 8 + 3] = r - cacc;
                    break;
                }
                cacc += loc[j];
            }
        }
    }
    grid.sync();

    // ---- P3: low-bit histogram filtered by mid
    {
        unsigned mid = ws[ST_OFF + b * 8 + 2];
        for (int j = tid; j < 1024; j += 256) shm[j] = 0;
        __syncthreads();
        for (int c = g; c < 1000; c += 64) {
            unsigned n = min(ws[GC_OFF + b * 1000 + c], CAPW);
            const unsigned* src = ou + (size_t)b * 1024000 + (size_t)c * 1024;
            for (unsigned i = tid; i < n; i += 256) {
                unsigned k = src[i];
                if (((k >> 10) & 0x7FFu) == mid) atomicAdd(&shm[k & 0x3FFu], 1u);
            }
        }
        __syncthreads();
        unsigned* gd = ws + H3_OFF + b * 1024;
        for (int j = tid; j < 1024; j += 256) if (shm[j]) atomicAdd(&gd[j], shm[j]);
    }
    grid.sync();

    // ---- P4: pick low -> k_hi
    if (g == 0) {
        const unsigned* hist = ws + H3_OFF + b * 1024;
        unsigned r = ws[ST_OFF + b * 8 + 3];
        unsigned loc[4], lsum = 0;
        for (int j = 0; j < 4; ++j) { loc[j] = hist[tid * 4 + j]; lsum += loc[j]; }
        shm[tid] = lsum; __syncthreads();
        for (int off = 1; off < 256; off <<= 1) {
            unsigned v = (tid >= off) ? shm[tid - off] : 0u; __syncthreads();
            shm[tid] += v; __syncthreads();
        }
        unsigned base = tid ? shm[tid - 1] : 0u;
        if (r >= base && r < base + lsum) {
            unsigned cacc = base;
            for (int j = 0; j < 4; ++j) {
                if (r < cacc + loc[j]) {
                    unsigned P = ws[ST_OFF + b * 8 + 0];
                    unsigned mid = ws[ST_OFF + b * 8 + 2];
                    ws[ST_OFF + b * 8 + 4] = (P << 21) | (mid << 10) | (unsigned)(tid * 4 + j);
                    break;
                }
                cacc += loc[j];
            }
        }
    }
    grid.sync();

    // ---- P5: per-slot ge/gt counts, one wave per slot
    {
        unsigned k_hi = ws[ST_OFF + b * 8 + 4];
        for (int c = (g << 2) + wid; c < 1000; c += 256) {
            unsigned n = min(ws[GC_OFF + b * 1000 + c], CAPW);
            const unsigned* src = ou + (size_t)b * 1024000 + (size_t)c * 1024;
            unsigned ge = 0, gt = 0;
            for (unsigned i = (unsigned)lane; i < n; i += 64u) {
                unsigned k = src[i];
                ge += (unsigned)(k >= k_hi);
                gt += (unsigned)(k > k_hi);
            }
            for (int off = 32; off > 0; off >>= 1) {
                ge += __shfl_down(ge, off, 64);
                gt += __shfl_down(gt, off, 64);
            }
            if (lane == 0) {
                ws[GE_OFF + b * 1000 + c] = ge;
                ws[GT_OFF + b * 1000 + c] = gt;
            }
        }
    }
    grid.sync();

    // ---- P6: tie decision + exclusive scan
    if (g == 0) {
        unsigned* above = ws + BC_OFF + b * 1000;
        const unsigned* ge = ws + GE_OFF + b * 1000;
        const unsigned* gt = ws + GT_OFF + b * 1000;
        unsigned la[4], lg[4], lh[4];
        for (int j = 0; j < 4; ++j) {
            int idx = tid * 4 + j;
            bool in = idx < 1000;
            la[j] = in ? above[idx] : 0u;
            lg[j] = in ? ge[idx] : 0u;
            lh[j] = in ? gt[idx] : 0u;
        }
        unsigned s1 = la[0] + lg[0] + la[1] + lg[1] + la[2] + lg[2] + la[3] + lg[3];
        shm[tid] = s1; __syncthreads();
        for (int off = 1; off < 256; off <<= 1) {
            unsigned v = (tid >= off) ? shm[tid - off] : 0u; __syncthreads();
            shm[tid] += v; __syncthreads();
        }
        unsigned TG = shm[255];
        __syncthreads();
        bool sel = (TG == NSEL);
        unsigned lc[4];
        for (int j = 0; j < 4; ++j) lc[j] = la[j] + (sel ? lg[j] : lh[j]);
        unsigned s2 = lc[0] + lc[1] + lc[2] + lc[3];
        shm[tid] = s2; __syncthreads();
        for (int off = 1; off < 256; off <<= 1) {
            unsigned v = (tid >= off) ? shm[tid - off] : 0u; __syncthreads();
            shm[tid] += v; __syncthreads();
        }
        unsigned run = tid ? shm[tid - 1] : 0u;
        for (int j = 0; j < 4; ++j) {
            int idx = tid * 4 + j;
            if (idx < 1000) above[idx] = run;
            run += lc[j];
        }
        if (tid == 255) ws[CNT_OFF + b] = shm[255];
        if (tid == 0) {
            unsigned kh = ws[ST_OFF + b * 8 + 4];
            ws[ST_OFF + b * 8 + 5] = sel ? kh : kh + 1u;
        }
    }
}

// ======= fallback (non-cooperative) versions of the refine phases =======
__global__ void hist2b_k(const unsigned* __restrict__ ou, unsigned* __restrict__ ws) {
    __shared__ unsigned h[2048];
    int tid = threadIdx.x, blk = blockIdx.x;
    int b = blk >> 6, g = blk & 63;
    for (int j = tid; j < 2048; j += 256) h[j] = 0;
    __syncthreads();
    for (int c = g; c < 1000; c += 64) {
        unsigned n = min(ws[GC_OFF + b * 1000 + c], CAPW);
        const unsigned* src = ou + (size_t)b * 1024000 + (size_t)c * 1024;
        for (unsigned i = tid; i < n; i += 256)
            atomicAdd(&h[(src[i] >> 10) & 0x7FFu], 1u);
    }
    __syncthreads();
    unsigned* gd = ws + H2_OFF + b * 2048;
    for (int j = tid; j < 2048; j += 256) if (h[j]) atomicAdd(&gd[j], h[j]);
}

__global__ void pick2b_k(unsigned* __restrict__ ws) {
    __shared__ unsigned sh[256];
    int tid = threadIdx.x, b = blockIdx.x;
    const unsigned* hist = ws + H2_OFF + b * 2048;
    unsigned r = ws[ST_OFF + b * 8 + 1];
    unsigned loc[8], lsum = 0;
    for (int j = 0; j < 8; ++j) { loc[j] = hist[tid * 8 + j]; lsum += loc[j]; }
    sh[tid] = lsum; __syncthreads();
    for (int off = 1; off < 256; off <<= 1) {
        unsigned v = (tid >= off) ? sh[tid - off] : 0u; __syncthreads();
        sh[tid] += v; __syncthreads();
    }
    unsigned base = tid ? sh[tid - 1] : 0u;
    if (r >= base && r < base + lsum) {
        unsigned cacc = base;
        for (int j = 0; j < 8; ++j) {
            if (r < cacc + loc[j]) {
                ws[ST_OFF + b * 8 + 2] = (unsigned)(tid * 8 + j);
                ws[ST_OFF + b * 8 + 3] = r - cacc;
                break;
            }
            cacc += loc[j];
        }
    }
}

__global__ void hist3b_k(const unsigned* __restrict__ ou, unsigned* __restrict__ ws) {
    __shared__ unsigned h[1024];
    int tid = threadIdx.x, blk = blockIdx.x;
    int b = blk >> 6, g = blk & 63;
    unsigned mid = ws[ST_OFF + b * 8 + 2];
    for (int j = tid; j < 1024; j += 256) h[j] = 0;
    __syncthreads();
    for (int c = g; c < 1000; c += 64) {
        unsigned n = min(ws[GC_OFF + b * 1000 + c], CAPW);
        const unsigned* src = ou + (size_t)b * 1024000 + (size_t)c * 1024;
        for (unsigned i = tid; i < n; i += 256) {
            unsigned k = src[i];
            if (((k >> 10) & 0x7FFu) == mid) atomicAdd(&h[k & 0x3FFu], 1u);
        }
    }
    __syncthreads();
    unsigned* gd = ws + H3_OFF + b * 1024;
    for (int j = tid; j < 1024; j += 256) if (h[j]) atomicAdd(&gd[j], h[j]);
}

__global__ void pick3b_k(unsigned* __restrict__ ws) {
    __shared__ unsigned sh[256];
    int tid = threadIdx.x, b = blockIdx.x;
    const unsigned* hist = ws + H3_OFF + b * 1024;
    unsigned r = ws[ST_OFF + b * 8 + 3];
    unsigned loc[4], lsum = 0;
    for (int j = 0; j < 4; ++j) { loc[j] = hist[tid * 4 + j]; lsum += loc[j]; }
    sh[tid] = lsum; __syncthreads();
    for (int off = 1; off < 256; off <<= 1) {
        unsigned v = (tid >= off) ? sh[tid - off] : 0u; __syncthreads();
        sh[tid] += v; __syncthreads();
    }
    unsigned base = tid ? sh[tid - 1] : 0u;
    if (r >= base && r < base + lsum) {
        unsigned cacc = base;
        for (int j = 0; j < 4; ++j) {
            if (r < cacc + loc[j]) {
                unsigned P = ws[ST_OFF + b * 8 + 0];
                unsigned mid = ws[ST_OFF + b * 8 + 2];
                ws[ST_OFF + b * 8 + 4] = (P << 21) | (mid << 10) | (unsigned)(tid * 4 + j);
                break;
            }
            cacc += loc[j];
        }
    }
}

__global__ void cand_bc_k(const unsigned* __restrict__ ou, unsigned* __restrict__ ws) {
    __shared__ unsigned sh[256];
    int tid = threadIdx.x, blk = blockIdx.x;
    int b = blk / 1000, c = blk % 1000;
    unsigned k_hi = ws[ST_OFF + b * 8 + 4];
    unsigned n = min(ws[GC_OFF + b * 1000 + c], CAPW);
    const unsigned* src = ou + (size_t)b * 1024000 + (size_t)c * 1024;
    unsigned ge = 0, gt = 0;
    for (unsigned i = tid; i < n; i += 256) {
        unsigned k = src[i];
        ge += (unsigned)(k >= k_hi);
        gt += (unsigned)(k > k_hi);
    }
    sh[tid] = (gt << 16) | ge;
    __syncthreads();
    for (int off = 128; off > 0; off >>= 1) {
        if (tid < off) sh[tid] += sh[tid + off];
        __syncthreads();
    }
    if (tid == 0) {
        ws[GE_OFF + b * 1000 + c] = sh[0] & 0xFFFFu;
        ws[GT_OFF + b * 1000 + c] = sh[0] >> 16;
    }
}

__global__ void scan_k(unsigned* __restrict__ ws) {
    __shared__ unsigned sh[256];
    int tid = threadIdx.x, b = blockIdx.x;
    unsigned* above = ws + BC_OFF + b * 1000;
    const unsigned* ge = ws + GE_OFF + b * 1000;
    const unsigned* gt = ws + GT_OFF + b * 1000;
    unsigned la[4], lg[4], lh[4];
    for (int j = 0; j < 4; ++j) {
        int idx = tid * 4 + j;
        bool in = idx < 1000;
        la[j] = in ? above[idx] : 0u;
        lg[j] = in ? ge[idx] : 0u;
        lh[j] = in ? gt[idx] : 0u;
    }
    unsigned s1 = la[0] + lg[0] + la[1] + lg[1] + la[2] + lg[2] + la[3] + lg[3];
    sh[tid] = s1; __syncthreads();
    for (int off = 1; off < 256; off <<= 1) {
        unsigned v = (tid >= off) ? sh[tid - off] : 0u; __syncthreads();
        sh[tid] += v; __syncthreads();
    }
    unsigned TG = sh[255];
    __syncthreads();
    bool sel = (TG == NSEL);
    unsigned lc[4];
    for (int j = 0; j < 4; ++j) lc[j] = la[j] + (sel ? lg[j] : lh[j]);
    unsigned s2 = lc[0] + lc[1] + lc[2] + lc[3];
    sh[tid] = s2; __syncthreads();
    for (int off = 1; off < 256; off <<= 1) {
        unsigned v = (tid >= off) ? sh[tid - off] : 0u; __syncthreads();
        sh[tid] += v; __syncthreads();
    }
    unsigned run = tid ? sh[tid - 1] : 0u;
    for (int j = 0; j < 4; ++j) {
        int idx = tid * 4 + j;
        if (idx < 1000) above[idx] = run;
        run += lc[j];
    }
    if (tid == 255) ws[CNT_OFF + b] = sh[255];
    if (tid == 0) {
        unsigned kh = ws[ST_OFF + b * 8 + 4];
        ws[ST_OFF + b * 8 + 5] = sel ? kh : kh + 1u;
    }
}

// ---------------- ordered scatter: index+value stash, dop-only gather, fused tail fill ----------------
__device__ __forceinline__ void emit_row(float* __restrict__ out, int b, unsigned k,
                                         int i, float x, float d) {
    size_t row = (size_t)b * Kn + k;
    int xi = i % 320;
    int t = i / 320;
    int yi = t % 320;
    int zi = t / 320;
    float* f = out + row * 5;
    f[0] = (float)xi / 320.0f * 72.0f;
    f[1] = (float)yi / 320.0f * 32.0f;
    f[2] = (float)zi / 40.0f * 8.0f;
    f[3] = x / 1e13f;
    f[4] = d - 1.9326f;
    float* s = out + OUT_SP + row * 4;
    s[0] = (float)b; s[1] = (float)zi; s[2] = (float)yi; s[3] = (float)xi;
    out[OUT_VAL + row] = 1.0f;
}

__global__ void scatter_k(const float* __restrict__ cube, const float* __restrict__ dop,
                          float* __restrict__ out, const unsigned* __restrict__ ws) {
    __shared__ float fbuf[SCAP * 5];
    __shared__ unsigned si[SCAP];
    __shared__ unsigned wcnt_sh[4];
    int tid = threadIdx.x, blk = blockIdx.x;
    int b = blk / 1000, c = blk % 1000;
    int lane = tid & 63, wid = tid >> 6;
    unsigned SELKEY = ws[ST_OFF + b * 8 + 5];

    size_t chunk = (size_t)b * Nn + (size_t)c * 4096 + (size_t)wid * 1024;
    const float4* pc = (const float4*)(cube + chunk);

    unsigned kk[16];
#pragma unroll
    for (int t = 0; t < 4; ++t) {
        float4 a = pc[t * 64 + lane];
        kk[4 * t + 0] = fkey(a.x); kk[4 * t + 1] = fkey(a.y);
        kk[4 * t + 2] = fkey(a.z); kk[4 * t + 3] = fkey(a.w);
    }
    unsigned long long bb[16];
    unsigned wcnt = 0;
#pragma unroll
    for (int j = 0; j < 16; ++j) {
        bb[j] = __ballot(kk[j] >= SELKEY);
        wcnt += (unsigned)__popcll(bb[j]);
    }
    if (lane == 0) wcnt_sh[wid] = wcnt;
    __syncthreads();

    unsigned k0 = ws[BC_OFF + b * 1000 + c];
    unsigned total = wcnt_sh[0] + wcnt_sh[1] + wcnt_sh[2] + wcnt_sh[3];
    unsigned wbase = 0;
    for (int w = 0; w < wid; ++w) wbase += wcnt_sh[w];

    unsigned long long lt = (1ull << lane) - 1ull;
    int i0base = c * 4096 + wid * 1024 + lane * 4;
    size_t row0 = (size_t)b * Kn + k0;

    if (total <= SCAP) {
        // divergent stash: element index AND power value (lane-major order per t-group)
        unsigned wb = wbase;
#pragma unroll
        for (int t = 0; t < 4; ++t) {
            bool m0 = kk[4 * t + 0] >= SELKEY, m1 = kk[4 * t + 1] >= SELKEY,
                 m2 = kk[4 * t + 2] >= SELKEY, m3 = kk[4 * t + 3] >= SELKEY;
            unsigned s_all = (unsigned)__popcll(bb[4 * t + 0] & lt) + (unsigned)__popcll(bb[4 * t + 1] & lt)
                           + (unsigned)__popcll(bb[4 * t + 2] & lt) + (unsigned)__popcll(bb[4 * t + 3] & lt);
            unsigned r = wb + s_all;
            int i0 = i0base + t * 256;
            if (m0) { si[r] = (unsigned)(i0 + 0); fbuf[r * 5 + 3] = keyf(kk[4 * t + 0]) / 1e13f; }
            r += (unsigned)m0;
            if (m1) { si[r] = (unsigned)(i0 + 1); fbuf[r * 5 + 3] = keyf(kk[4 * t + 1]) / 1e13f; }
            r += (unsigned)m1;
            if (m2) { si[r] = (unsigned)(i0 + 2); fbuf[r * 5 + 3] = keyf(kk[4 * t + 2]) / 1e13f; }
            r += (unsigned)m2;
            if (m3) { si[r] = (unsigned)(i0 + 3); fbuf[r * 5 + 3] = keyf(kk[4 * t + 3]) / 1e13f; }
            wb += (unsigned)__popcll(bb[4 * t + 0]) + (unsigned)__popcll(bb[4 * t + 1])
                + (unsigned)__popcll(bb[4 * t + 2]) + (unsigned)__popcll(bb[4 * t + 3]);
        }
        __syncthreads();

        // dense per-row phase: only dop gathered; sp-row written directly as float4
        const float* db = dop + (size_t)b * Nn;
        float fb = (float)b;
        for (unsigned r = tid; r < total; r += 256) {
            unsigned i = si[r];
            float d = db[i];
            unsigned xi = i % 320u;
            unsigned tt = i / 320u;
            unsigned yi = tt % 320u;
            unsigned zi = tt / 320u;
            fbuf[r * 5 + 0] = (float)xi / 320.0f * 72.0f;
            fbuf[r * 5 + 1] = (float)yi / 320.0f * 32.0f;
            fbuf[r * 5 + 2] = (float)zi / 40.0f * 8.0f;
            fbuf[r * 5 + 4] = d - 1.9326f;
            float4 sp = make_float4(fb, (float)zi, (float)yi, (float)xi);
            *(float4*)(out + OUT_SP + (row0 + r) * 4) = sp;   // 16B aligned
            out[OUT_VAL + row0 + r] = 1.0f;
        }
        __syncthreads();

        // feats region: linear coalesced copy
        float* f0 = out + row0 * 5;
        int total5 = (int)(total * 5);
        for (int j = tid; j < total5; j += 256) f0[j] = fbuf[j];
    } else {
        // fallback: direct scattered emit (never taken on bench data)
        const float4* pd = (const float4*)(dop + chunk);
        unsigned wb = k0 + wbase;
#pragma unroll
        for (int t = 0; t < 4; ++t) {
            float4 a = pc[t * 64 + lane];
            float4 d4 = pd[t * 64 + lane];
            float vvv[4] = {a.x, a.y, a.z, a.w};
            float ddd[4] = {d4.x, d4.y, d4.z, d4.w};
            bool m0 = kk[4 * t + 0] >= SELKEY, m1 = kk[4 * t + 1] >= SELKEY,
                 m2 = kk[4 * t + 2] >= SELKEY, m3 = kk[4 * t + 3] >= SELKEY;
            unsigned s_all = (unsigned)__popcll(bb[4 * t + 0] & lt) + (unsigned)__popcll(bb[4 * t + 1] & lt)
                           + (unsigned)__popcll(bb[4 * t + 2] & lt) + (unsigned)__popcll(bb[4 * t + 3] & lt);
            unsigned r = wb + s_all;
            int i0 = i0base + t * 256;
            if (m0) emit_row(out, b, r, i0 + 0, vvv[0], ddd[0]);
            r += (unsigned)m0;
            if (m1) emit_row(out, b, r, i0 + 1, vvv[1], ddd[1]);
            r += (unsigned)m1;
            if (m2) emit_row(out, b, r, i0 + 2, vvv[2], ddd[2]);
            r += (unsigned)m2;
            if (m3) emit_row(out, b, r, i0 + 3, vvv[3], ddd[3]);
            wb += (unsigned)__popcll(bb[4 * t + 0]) + (unsigned)__popcll(bb[4 * t + 1])
                + (unsigned)__popcll(bb[4 * t + 2]) + (unsigned)__popcll(bb[4 * t + 3]);
        }
    }

    // fused tail fill (block c==999 zeroes invalid rows [cnt, Kn) of its sample)
    if (c == 999) {
        unsigned cnt = ws[CNT_OFF + b];
        size_t base = (size_t)b * Kn;
        for (unsigned r = cnt + tid; r < Kn; r += 256) {
            float* f = out + (base + r) * 5;
            f[0] = 0.f; f[1] = 0.f; f[2] = 0.f; f[3] = 0.f; f[4] = 0.f;
            *(float4*)(out + OUT_SP + (base + r) * 4) = make_float4(0.f, 0.f, 0.f, 0.f);
            out[OUT_VAL + base + r] = 0.f;
        }
    }
}

extern "C" void kernel_launch(void* const* d_in, const int* in_sizes, int n_in,
                              void* d_out, int out_size, void* d_ws, size_t ws_size,
                              hipStream_t stream) {
    const float* cube = (const float*)d_in[0];
    const float* dop = (const float*)d_in[1];
    float* out = (float*)d_out;
    unsigned* ws = (unsigned*)d_ws;
    unsigned* ou = (unsigned*)d_out;

    hipMemsetAsync(d_ws, 0, ZERO_WORDS * sizeof(unsigned), stream);

    hipLaunchKernelGGL(hist1_k, dim3(Bn * 250), dim3(256), 0, stream, cube, ws);
    hipLaunchKernelGGL(pick1_k, dim3(Bn), dim3(256), 0, stream, ws);
    hipLaunchKernelGGL(collect_k, dim3(Bn * 1000), dim3(256), 0, stream, cube, ou, ws);

    {
        const unsigned* ouc = (const unsigned*)d_out;
        unsigned* wsp = ws;
        void* args[] = {(void*)&ouc, (void*)&wsp};
        hipError_t rc = hipLaunchCooperativeKernel((const void*)refine_k, dim3(Bn * 64), dim3(256),
                                                   args, 0, stream);
        if (rc != hipSuccess) {
            // fallback: individual kernels (same math)
            hipLaunchKernelGGL(hist2b_k, dim3(Bn * 64), dim3(256), 0, stream, ou, ws);
            hipLaunchKernelGGL(pick2b_k, dim3(Bn), dim3(256), 0, stream, ws);
            hipLaunchKernelGGL(hist3b_k, dim3(Bn * 64), dim3(256), 0, stream, ou, ws);
            hipLaunchKernelGGL(pick3b_k, dim3(Bn), dim3(256), 0, stream, ws);
            hipLaunchKernelGGL(cand_bc_k, dim3(Bn * 1000), dim3(256), 0, stream, ou, ws);
            hipLaunchKernelGGL(scan_k, dim3(Bn), dim3(256), 0, stream, ws);
        }
    }

    hipLaunchKernelGGL(scatter_k, dim3(Bn * 1000), dim3(256), 0, stream, cube, dop, out, ws);
}

// Round 10
// 237.283 us; speedup vs baseline: 1.6353x; 1.6353x over previous
//
#include <hip/hip_runtime.h>

#define Bn 4
#define Nn 4096000
#define Kn 409664
#define R1c 3686400u
#define NSEL 409600u

// ---- ws offsets (u32 units) ----
#define H1_OFF 0          // B*2048
#define H2_OFF 8192       // B*2048
#define H3_OFF 16384      // B*1024
#define ZERO_WORDS 20480
#define ST_OFF 20480      // B*8: 0=P,1=rem,2=mid,3=rem2,4=k_hi,5=SELKEY
#define BC_OFF 20512      // B*1000 (above counts -> scanned bc)
#define GE_OFF 24512      // B*1000
#define GT_OFF 28512      // B*1000
#define GC_OFF 32512      // B*1000 (candidate count per block)
#define CNT_OFF 36512     // B

// ---- deterministic candidate slots inside `out` (u32 units) ----
#define CAPW 1024u

#define SCAP 768          // max buffered rows per scatter block

#define OUT_SP  ((size_t)Bn * Kn * 5)
#define OUT_VAL ((size_t)Bn * Kn * 9)

__device__ __forceinline__ unsigned fkey(float x) {
    unsigned u = __float_as_uint(x);
    return u ^ ((unsigned)((int)u >> 31) | 0x80000000u);
}
__device__ __forceinline__ float keyf(unsigned k) {
    unsigned u = (k & 0x80000000u) ? (k & 0x7FFFFFFFu) : ~k;
    return __uint_as_float(u);
}

// ---------------- histogram pass 1: top 11 bits ----------------
__device__ __forceinline__ void h1add(unsigned* h, unsigned cp, float v) {
    unsigned bin = fkey(v) >> 21;
    atomicAdd(&h[(cp << 11) + ((bin + (cp << 3)) & 2047u)], 1u);
}

__global__ void hist1_k(const float* __restrict__ cube, unsigned* __restrict__ ws) {
    __shared__ unsigned h[4 * 2048];
    int tid = threadIdx.x, blk = blockIdx.x;
    int b = blk / 250, c = blk % 250;
    unsigned cp = (unsigned)(tid & 3);
    for (int j = tid; j < 8192; j += 256) h[j] = 0;
    __syncthreads();
    const float4* p = (const float4*)(cube + (size_t)b * Nn + (size_t)c * 16384);
    for (int it = 0; it < 16; it += 4) {
        float4 v0 = p[(it + 0) * 256 + tid];
        float4 v1 = p[(it + 1) * 256 + tid];
        float4 v2 = p[(it + 2) * 256 + tid];
        float4 v3 = p[(it + 3) * 256 + tid];
        h1add(h, cp, v0.x); h1add(h, cp, v0.y); h1add(h, cp, v0.z); h1add(h, cp, v0.w);
        h1add(h, cp, v1.x); h1add(h, cp, v1.y); h1add(h, cp, v1.z); h1add(h, cp, v1.w);
        h1add(h, cp, v2.x); h1add(h, cp, v2.y); h1add(h, cp, v2.z); h1add(h, cp, v2.w);
        h1add(h, cp, v3.x); h1add(h, cp, v3.y); h1add(h, cp, v3.z); h1add(h, cp, v3.w);
    }
    __syncthreads();
    unsigned* g = ws + H1_OFF + b * 2048;
    for (int j = tid; j < 2048; j += 256) {
        unsigned s = 0;
#pragma unroll
        for (int k = 0; k < 4; ++k) s += h[(k << 11) + (((unsigned)j + (k << 3)) & 2047u)];
        if (s) atomicAdd(&g[j], s);
    }
}

// ---------------- pick bucket containing rank R1c ----------------
__global__ void pick1_k(unsigned* __restrict__ ws) {
    __shared__ unsigned sh[256];
    int tid = threadIdx.x, b = blockIdx.x;
    const unsigned* hist = ws + H1_OFF + b * 2048;
    unsigned loc[8], lsum = 0;
    for (int j = 0; j < 8; ++j) { loc[j] = hist[tid * 8 + j]; lsum += loc[j]; }
    sh[tid] = lsum; __syncthreads();
    for (int off = 1; off < 256; off <<= 1) {
        unsigned v = (tid >= off) ? sh[tid - off] : 0u; __syncthreads();
        sh[tid] += v; __syncthreads();
    }
    unsigned base = tid ? sh[tid - 1] : 0u;
    if (R1c >= base && R1c < base + lsum) {
        unsigned cacc = base;
        for (int j = 0; j < 8; ++j) {
            if (R1c < cacc + loc[j]) {
                ws[ST_OFF + b * 8 + 0] = (unsigned)(tid * 8 + j);
                ws[ST_OFF + b * 8 + 1] = R1c - cacc;
                break;
            }
            cacc += loc[j];
        }
    }
}

// ---------------- collect: deterministic slots, zero global atomics ----------------
__global__ void collect_k(const float* __restrict__ cube, unsigned* __restrict__ ou,
                          unsigned* __restrict__ ws) {
    __shared__ unsigned sha[4], shc[4];
    int tid = threadIdx.x, blk = blockIdx.x;
    int b = blk / 1000, c = blk % 1000;
    int lane = tid & 63, wid = tid >> 6;
    unsigned P = ws[ST_OFF + b * 8 + 0];
    const float4* pc = (const float4*)(cube + (size_t)b * Nn + (size_t)c * 4096 + (size_t)wid * 1024);
    unsigned kk[16];
#pragma unroll
    for (int t = 0; t < 4; ++t) {
        float4 v = pc[t * 64 + lane];
        kk[4 * t + 0] = fkey(v.x); kk[4 * t + 1] = fkey(v.y);
        kk[4 * t + 2] = fkey(v.z); kk[4 * t + 3] = fkey(v.w);
    }
    unsigned long long bc[16];
    unsigned wab = 0, wcn = 0;
#pragma unroll
    for (int j = 0; j < 16; ++j) {
        unsigned top = kk[j] >> 21;
        wab += (unsigned)__popcll(__ballot(top > P));
        bc[j] = __ballot(top == P);
        wcn += (unsigned)__popcll(bc[j]);
    }
    if (lane == 0) { sha[wid] = wab; shc[wid] = wcn; }
    __syncthreads();
    if (tid == 0) {
        ws[BC_OFF + b * 1000 + c] = sha[0] + sha[1] + sha[2] + sha[3];
        ws[GC_OFF + b * 1000 + c] = shc[0] + shc[1] + shc[2] + shc[3];
    }
    unsigned run = 0;
    for (int w = 0; w < wid; ++w) run += shc[w];
    unsigned long long lt = (1ull << lane) - 1ull;
    unsigned* dst = ou + (size_t)b * 1024000 + (size_t)c * 1024;
#pragma unroll
    for (int j = 0; j < 16; ++j) {
        bool m = (kk[j] >> 21) == P;
        unsigned r = run + (unsigned)__popcll(bc[j] & lt);
        if (m && r < CAPW) dst[r] = kk[j];
        run += (unsigned)__popcll(bc[j]);
    }
}

// ---------------- refine A: bits [20:10] over candidate slots ----------------
__global__ void hist2b_k(const unsigned* __restrict__ ou, unsigned* __restrict__ ws) {
    __shared__ unsigned h[2048];
    int tid = threadIdx.x, blk = blockIdx.x;
    int b = blk >> 6, g = blk & 63;
    for (int j = tid; j < 2048; j += 256) h[j] = 0;
    __syncthreads();
    for (int c = g; c < 1000; c += 64) {
        unsigned n = min(ws[GC_OFF + b * 1000 + c], CAPW);
        const unsigned* src = ou + (size_t)b * 1024000 + (size_t)c * 1024;
        for (unsigned i = tid; i < n; i += 256)
            atomicAdd(&h[(src[i] >> 10) & 0x7FFu], 1u);
    }
    __syncthreads();
    unsigned* gd = ws + H2_OFF + b * 2048;
    for (int j = tid; j < 2048; j += 256) if (h[j]) atomicAdd(&gd[j], h[j]);
}

__global__ void pick2b_k(unsigned* __restrict__ ws) {
    __shared__ unsigned sh[256];
    int tid = threadIdx.x, b = blockIdx.x;
    const unsigned* hist = ws + H2_OFF + b * 2048;
    unsigned r = ws[ST_OFF + b * 8 + 1];
    unsigned loc[8], lsum = 0;
    for (int j = 0; j < 8; ++j) { loc[j] = hist[tid * 8 + j]; lsum += loc[j]; }
    sh[tid] = lsum; __syncthreads();
    for (int off = 1; off < 256; off <<= 1) {
        unsigned v = (tid >= off) ? sh[tid - off] : 0u; __syncthreads();
        sh[tid] += v; __syncthreads();
    }
    unsigned base = tid ? sh[tid - 1] : 0u;
    if (r >= base && r < base + lsum) {
        unsigned cacc = base;
        for (int j = 0; j < 8; ++j) {
            if (r < cacc + loc[j]) {
                ws[ST_OFF + b * 8 + 2] = (unsigned)(tid * 8 + j);
                ws[ST_OFF + b * 8 + 3] = r - cacc;
                break;
            }
            cacc += loc[j];
        }
    }
}

// ---------------- refine B: low 10 bits ----------------
__global__ void hist3b_k(const unsigned* __restrict__ ou, unsigned* __restrict__ ws) {
    __shared__ unsigned h[1024];
    int tid = threadIdx.x, blk = blockIdx.x;
    int b = blk >> 6, g = blk & 63;
    unsigned mid = ws[ST_OFF + b * 8 + 2];
    for (int j = tid; j < 1024; j += 256) h[j] = 0;
    __syncthreads();
    for (int c = g; c < 1000; c += 64) {
        unsigned n = min(ws[GC_OFF + b * 1000 + c], CAPW);
        const unsigned* src = ou + (size_t)b * 1024000 + (size_t)c * 1024;
        for (unsigned i = tid; i < n; i += 256) {
            unsigned k = src[i];
            if (((k >> 10) & 0x7FFu) == mid) atomicAdd(&h[k & 0x3FFu], 1u);
        }
    }
    __syncthreads();
    unsigned* gd = ws + H3_OFF + b * 1024;
    for (int j = tid; j < 1024; j += 256) if (h[j]) atomicAdd(&gd[j], h[j]);
}

__global__ void pick3b_k(unsigned* __restrict__ ws) {
    __shared__ unsigned sh[256];
    int tid = threadIdx.x, b = blockIdx.x;
    const unsigned* hist = ws + H3_OFF + b * 1024;
    unsigned r = ws[ST_OFF + b * 8 + 3];
    unsigned loc[4], lsum = 0;
    for (int j = 0; j < 4; ++j) { loc[j] = hist[tid * 4 + j]; lsum += loc[j]; }
    sh[tid] = lsum; __syncthreads();
    for (int off = 1; off < 256; off <<= 1) {
        unsigned v = (tid >= off) ? sh[tid - off] : 0u; __syncthreads();
        sh[tid] += v; __syncthreads();
    }
    unsigned base = tid ? sh[tid - 1] : 0u;
    if (r >= base && r < base + lsum) {
        unsigned cacc = base;
        for (int j = 0; j < 4; ++j) {
            if (r < cacc + loc[j]) {
                unsigned P = ws[ST_OFF + b * 8 + 0];
                unsigned mid = ws[ST_OFF + b * 8 + 2];
                ws[ST_OFF + b * 8 + 4] = (P << 21) | (mid << 10) | (unsigned)(tid * 4 + j);
                break;
            }
            cacc += loc[j];
        }
    }
}

// ---------------- per-block candidate counts (>=k_hi and >k_hi) ----------------
__global__ void cand_bc_k(const unsigned* __restrict__ ou, unsigned* __restrict__ ws) {
    __shared__ unsigned sh[256];
    int tid = threadIdx.x, blk = blockIdx.x;
    int b = blk / 1000, c = blk % 1000;
    unsigned k_hi = ws[ST_OFF + b * 8 + 4];
    unsigned n = min(ws[GC_OFF + b * 1000 + c], CAPW);
    const unsigned* src = ou + (size_t)b * 1024000 + (size_t)c * 1024;
    unsigned ge = 0, gt = 0;
    for (unsigned i = tid; i < n; i += 256) {
        unsigned k = src[i];
        ge += (unsigned)(k >= k_hi);
        gt += (unsigned)(k > k_hi);
    }
    sh[tid] = (gt << 16) | ge;  // counts <= 1024, packed sum safe
    __syncthreads();
    for (int off = 128; off > 0; off >>= 1) {
        if (tid < off) sh[tid] += sh[tid + off];
        __syncthreads();
    }
    if (tid == 0) {
        ws[GE_OFF + b * 1000 + c] = sh[0] & 0xFFFFu;
        ws[GT_OFF + b * 1000 + c] = sh[0] >> 16;
    }
}

// ---------------- scan: decide SELKEY (tie case), exclusive scan of block counts ----------------
__global__ void scan_k(unsigned* __restrict__ ws) {
    __shared__ unsigned sh[256];
    int tid = threadIdx.x, b = blockIdx.x;
    unsigned* above = ws + BC_OFF + b * 1000;
    const unsigned* ge = ws + GE_OFF + b * 1000;
    const unsigned* gt = ws + GT_OFF + b * 1000;
    unsigned la[4], lg[4], lh[4];
    for (int j = 0; j < 4; ++j) {
        int idx = tid * 4 + j;
        bool in = idx < 1000;
        la[j] = in ? above[idx] : 0u;
        lg[j] = in ? ge[idx] : 0u;
        lh[j] = in ? gt[idx] : 0u;
    }
    unsigned s1 = la[0] + lg[0] + la[1] + lg[1] + la[2] + lg[2] + la[3] + lg[3];
    sh[tid] = s1; __syncthreads();
    for (int off = 1; off < 256; off <<= 1) {
        unsigned v = (tid >= off) ? sh[tid - off] : 0u; __syncthreads();
        sh[tid] += v; __syncthreads();
    }
    unsigned TG = sh[255];
    __syncthreads();
    bool sel = (TG == NSEL);   // vlo < vhi => select key >= k_hi ; tie => key > k_hi
    unsigned lc[4];
    for (int j = 0; j < 4; ++j) lc[j] = la[j] + (sel ? lg[j] : lh[j]);
    unsigned s2 = lc[0] + lc[1] + lc[2] + lc[3];
    sh[tid] = s2; __syncthreads();
    for (int off = 1; off < 256; off <<= 1) {
        unsigned v = (tid >= off) ? sh[tid - off] : 0u; __syncthreads();
        sh[tid] += v; __syncthreads();
    }
    unsigned run = tid ? sh[tid - 1] : 0u;
    for (int j = 0; j < 4; ++j) {
        int idx = tid * 4 + j;
        if (idx < 1000) above[idx] = run;
        run += lc[j];
    }
    if (tid == 255) ws[CNT_OFF + b] = sh[255];
    if (tid == 0) {
        unsigned kh = ws[ST_OFF + b * 8 + 4];
        ws[ST_OFF + b * 8 + 5] = sel ? kh : kh + 1u;
    }
}

// ---------------- ordered scatter: index+value stash, dop-only gather, fused tail fill ----------------
__device__ __forceinline__ void emit_row(float* __restrict__ out, int b, unsigned k,
                                         int i, float x, float d) {
    size_t row = (size_t)b * Kn + k;
    int xi = i % 320;
    int t = i / 320;
    int yi = t % 320;
    int zi = t / 320;
    float* f = out + row * 5;
    f[0] = (float)xi / 320.0f * 72.0f;
    f[1] = (float)yi / 320.0f * 32.0f;
    f[2] = (float)zi / 40.0f * 8.0f;
    f[3] = x / 1e13f;
    f[4] = d - 1.9326f;
    float* s = out + OUT_SP + row * 4;
    s[0] = (float)b; s[1] = (float)zi; s[2] = (float)yi; s[3] = (float)xi;
    out[OUT_VAL + row] = 1.0f;
}

__global__ void scatter_k(const float* __restrict__ cube, const float* __restrict__ dop,
                          float* __restrict__ out, const unsigned* __restrict__ ws) {
    __shared__ float fbuf[SCAP * 5];
    __shared__ unsigned si[SCAP];
    __shared__ unsigned wcnt_sh[4];
    int tid = threadIdx.x, blk = blockIdx.x;
    int b = blk / 1000, c = blk % 1000;
    int lane = tid & 63, wid = tid >> 6;
    unsigned SELKEY = ws[ST_OFF + b * 8 + 5];

    size_t chunk = (size_t)b * Nn + (size_t)c * 4096 + (size_t)wid * 1024;
    const float4* pc = (const float4*)(cube + chunk);

    unsigned kk[16];
#pragma unroll
    for (int t = 0; t < 4; ++t) {
        float4 a = pc[t * 64 + lane];
        kk[4 * t + 0] = fkey(a.x); kk[4 * t + 1] = fkey(a.y);
        kk[4 * t + 2] = fkey(a.z); kk[4 * t + 3] = fkey(a.w);
    }
    unsigned long long bb[16];
    unsigned wcnt = 0;
#pragma unroll
    for (int j = 0; j < 16; ++j) {
        bb[j] = __ballot(kk[j] >= SELKEY);
        wcnt += (unsigned)__popcll(bb[j]);
    }
    if (lane == 0) wcnt_sh[wid] = wcnt;
    __syncthreads();

    unsigned k0 = ws[BC_OFF + b * 1000 + c];
    unsigned total = wcnt_sh[0] + wcnt_sh[1] + wcnt_sh[2] + wcnt_sh[3];
    unsigned wbase = 0;
    for (int w = 0; w < wid; ++w) wbase += wcnt_sh[w];

    unsigned long long lt = (1ull << lane) - 1ull;
    int i0base = c * 4096 + wid * 1024 + lane * 4;
    size_t row0 = (size_t)b * Kn + k0;

    if (total <= SCAP) {
        // divergent stash: element index AND power value (lane-major order per t-group)
        unsigned wb = wbase;
#pragma unroll
        for (int t = 0; t < 4; ++t) {
            bool m0 = kk[4 * t + 0] >= SELKEY, m1 = kk[4 * t + 1] >= SELKEY,
                 m2 = kk[4 * t + 2] >= SELKEY, m3 = kk[4 * t + 3] >= SELKEY;
            unsigned s_all = (unsigned)__popcll(bb[4 * t + 0] & lt) + (unsigned)__popcll(bb[4 * t + 1] & lt)
                           + (unsigned)__popcll(bb[4 * t + 2] & lt) + (unsigned)__popcll(bb[4 * t + 3] & lt);
            unsigned r = wb + s_all;
            int i0 = i0base + t * 256;
            if (m0) { si[r] = (unsigned)(i0 + 0); fbuf[r * 5 + 3] = keyf(kk[4 * t + 0]) / 1e13f; }
            r += (unsigned)m0;
            if (m1) { si[r] = (unsigned)(i0 + 1); fbuf[r * 5 + 3] = keyf(kk[4 * t + 1]) / 1e13f; }
            r += (unsigned)m1;
            if (m2) { si[r] = (unsigned)(i0 + 2); fbuf[r * 5 + 3] = keyf(kk[4 * t + 2]) / 1e13f; }
            r += (unsigned)m2;
            if (m3) { si[r] = (unsigned)(i0 + 3); fbuf[r * 5 + 3] = keyf(kk[4 * t + 3]) / 1e13f; }
            wb += (unsigned)__popcll(bb[4 * t + 0]) + (unsigned)__popcll(bb[4 * t + 1])
                + (unsigned)__popcll(bb[4 * t + 2]) + (unsigned)__popcll(bb[4 * t + 3]);
        }
        __syncthreads();

        // dense per-row phase: only dop gathered; sp-row written directly as float4
        const float* db = dop + (size_t)b * Nn;
        float fb = (float)b;
        for (unsigned r = tid; r < total; r += 256) {
            unsigned i = si[r];
            float d = db[i];
            unsigned xi = i % 320u;
            unsigned tt = i / 320u;
            unsigned yi = tt % 320u;
            unsigned zi = tt / 320u;
            fbuf[r * 5 + 0] = (float)xi / 320.0f * 72.0f;
            fbuf[r * 5 + 1] = (float)yi / 320.0f * 32.0f;
            fbuf[r * 5 + 2] = (float)zi / 40.0f * 8.0f;
            fbuf[r * 5 + 4] = d - 1.9326f;
            float4 sp = make_float4(fb, (float)zi, (float)yi, (float)xi);
            *(float4*)(out + OUT_SP + (row0 + r) * 4) = sp;   // 16B aligned
            out[OUT_VAL + row0 + r] = 1.0f;
        }
        __syncthreads();

        // feats region: linear coalesced copy
        float* f0 = out + row0 * 5;
        int total5 = (int)(total * 5);
        for (int j = tid; j < total5; j += 256) f0[j] = fbuf[j];
    } else {
        // fallback: direct scattered emit (never taken on bench data)
        const float4* pd = (const float4*)(dop + chunk);
        unsigned wb = k0 + wbase;
#pragma unroll
        for (int t = 0; t < 4; ++t) {
            float4 a = pc[t * 64 + lane];
            float4 d4 = pd[t * 64 + lane];
            float vvv[4] = {a.x, a.y, a.z, a.w};
            float ddd[4] = {d4.x, d4.y, d4.z, d4.w};
            bool m0 = kk[4 * t + 0] >= SELKEY, m1 = kk[4 * t + 1] >= SELKEY,
                 m2 = kk[4 * t + 2] >= SELKEY, m3 = kk[4 * t + 3] >= SELKEY;
            unsigned s_all = (unsigned)__popcll(bb[4 * t + 0] & lt) + (unsigned)__popcll(bb[4 * t + 1] & lt)
                           + (unsigned)__popcll(bb[4 * t + 2] & lt) + (unsigned)__popcll(bb[4 * t + 3] & lt);
            unsigned r = wb + s_all;
            int i0 = i0base + t * 256;
            if (m0) emit_row(out, b, r, i0 + 0, vvv[0], ddd[0]);
            r += (unsigned)m0;
            if (m1) emit_row(out, b, r, i0 + 1, vvv[1], ddd[1]);
            r += (unsigned)m1;
            if (m2) emit_row(out, b, r, i0 + 2, vvv[2], ddd[2]);
            r += (unsigned)m2;
            if (m3) emit_row(out, b, r, i0 + 3, vvv[3], ddd[3]);
            wb += (unsigned)__popcll(bb[4 * t + 0]) + (unsigned)__popcll(bb[4 * t + 1])
                + (unsigned)__popcll(bb[4 * t + 2]) + (unsigned)__popcll(bb[4 * t + 3]);
        }
    }

    // fused tail fill (block c==999 zeroes invalid rows [cnt, Kn) of its sample)
    if (c == 999) {
        unsigned cnt = ws[CNT_OFF + b];
        size_t base = (size_t)b * Kn;
        for (unsigned r = cnt + tid; r < Kn; r += 256) {
            float* f = out + (base + r) * 5;
            f[0] = 0.f; f[1] = 0.f; f[2] = 0.f; f[3] = 0.f; f[4] = 0.f;
            *(float4*)(out + OUT_SP + (base + r) * 4) = make_float4(0.f, 0.f, 0.f, 0.f);
            out[OUT_VAL + base + r] = 0.f;
        }
    }
}

extern "C" void kernel_launch(void* const* d_in, const int* in_sizes, int n_in,
                              void* d_out, int out_size, void* d_ws, size_t ws_size,
                              hipStream_t stream) {
    const float* cube = (const float*)d_in[0];
    const float* dop = (const float*)d_in[1];
    float* out = (float*)d_out;
    unsigned* ws = (unsigned*)d_ws;
    unsigned* ou = (unsigned*)d_out;

    hipMemsetAsync(d_ws, 0, ZERO_WORDS * sizeof(unsigned), stream);

    hipLaunchKernelGGL(hist1_k, dim3(Bn * 250), dim3(256), 0, stream, cube, ws);
    hipLaunchKernelGGL(pick1_k, dim3(Bn), dim3(256), 0, stream, ws);
    hipLaunchKernelGGL(collect_k, dim3(Bn * 1000), dim3(256), 0, stream, cube, ou, ws);
    hipLaunchKernelGGL(hist2b_k, dim3(Bn * 64), dim3(256), 0, stream, ou, ws);
    hipLaunchKernelGGL(pick2b_k, dim3(Bn), dim3(256), 0, stream, ws);
    hipLaunchKernelGGL(hist3b_k, dim3(Bn * 64), dim3(256), 0, stream, ou, ws);
    hipLaunchKernelGGL(pick3b_k, dim3(Bn), dim3(256), 0, stream, ws);
    hipLaunchKernelGGL(cand_bc_k, dim3(Bn * 1000), dim3(256), 0, stream, ou, ws);
    hipLaunchKernelGGL(scan_k, dim3(Bn), dim3(256), 0, stream, ws);
    hipLaunchKernelGGL(scatter_k, dim3(Bn * 1000), dim3(256), 0, stream, cube, dop, out, ws);
}